// Round 3
// baseline (316.266 us; speedup 1.0000x reference)
//
#include <hip/hip_runtime.h>
#include <math.h>

#define B_ 3
#define P_ 768
#define F_ 1024
#define H_ 128
#define W_ 128
#define HW_ (H_*W_)
#define EPS_ 1e-8f

// Output layout (flat concat, floats):
//   imrender (1,128,128,3) : offset 0,      49152
//   improb   (128,128,1)   : offset 49152,  16384
//   normals  (3,1024,3)    : offset 65536,   9216
//   fg       (1,128,128,1) : offset 74752,  16384
#define OFF_PROB   49152
#define OFF_NORM   65536
#define OFF_FG     74752

// Workspace layout (bytes):
//   faceA: B*F float4  (e0x,e0y,e1x,e1y)        @ 0       (49152 B)
//   faceB: B*F float4  (cx,cy,denom,validflag)  @ 49152
//   faceC: B*F float4  (z0,z1,z2,0)             @ 98304
//   img:   B*HW float4 (r,g,b,mask)             @ 147456  (786432 B)

__global__ __launch_bounds__(256) void setup_faces(
    const float* __restrict__ points,
    const float* __restrict__ camrot,
    const float* __restrict__ campos,
    const float* __restrict__ proj,
    const int*   __restrict__ faces,
    float4* __restrict__ faceA,
    float4* __restrict__ faceB,
    float4* __restrict__ faceC,
    float*  __restrict__ normals_out)
{
#pragma clang fp contract(off)
    int t = blockIdx.x * blockDim.x + threadIdx.x;
    if (t >= B_ * F_) return;
    int b = t / F_;
    int f = t - b * F_;

    const float* R = camrot + b * 9;
    float cpx = campos[b*3+0], cpy = campos[b*3+1], cpz = campos[b*3+2];
    float pj0 = proj[0], pj1 = proj[1];

    float pcx[3], pcy[3], pcz[3], sx[3], sy[3];
    for (int v = 0; v < 3; ++v) {
        int vi = faces[f*3 + v];
        const float* P = points + (b*P_ + vi) * 3;
        float vx = P[0] - cpx;
        float vy = P[1] - cpy;
        float vz = P[2] - cpz;
        // (pts - campos) @ camrot.T  -> pc_j = (v0*Rj0 + v1*Rj1) + v2*Rj2
        float qx = (vx*R[0] + vy*R[1]) + vz*R[2];
        float qy = (vx*R[3] + vy*R[4]) + vz*R[5];
        float qz = (vx*R[6] + vy*R[7]) + vz*R[8];
        pcx[v] = qx; pcy[v] = qy; pcz[v] = qz;
        float dz = qz + EPS_;
        sx[v] = (qx * pj0) / dz;
        sy[v] = (qy * pj1) / dz;
    }

    float ax = sx[0], ay = sy[0];
    float bx = sx[1], by = sy[1];
    float cx = sx[2], cy = sy[2];

    float e0x = by - cy;           // (by - cy)
    float e0y = cx - bx;           // (cx - bx)
    float e1x = cy - ay;           // (cy - ay)
    float e1y = ax - cx;           // (ax - cx)
    float d = e0x*(ax - cx) + e0y*(ay - cy);
    float denom = d + EPS_;
    float valid = (fabsf(d) > EPS_) ? 1.0f : 0.0f;

    faceA[t] = make_float4(e0x, e0y, e1x, e1y);
    faceB[t] = make_float4(cx, cy, denom, valid);
    faceC[t] = make_float4(pcz[0], pcz[1], pcz[2], 0.0f);

    // normal = cross(v1-v0, v2-v0), normalized with +eps.
    // The reference (XLA-compiled) CONTRACTS a1*b2 - a2*b1 into
    // fma(a1, b2, -fl(a2*b1)) (LLVM fuses the LHS mul of an fsub first).
    // For faces with a duplicated vertex index (u == w bitwise) the exact
    // cross is 0 but the contracted form leaves the product-rounding
    // residual -e_ab = -(fl(a*b) - a*b), which the +1e-8 normalization
    // blows up to O(0.449) — the observed ref value. Rounds 1 (f32 exact)
    // and 2 (f64) both produced 0 there and failed with identical absmax,
    // confirming ref != 0. So: emulate the LHS-fma contraction explicitly.
    float ux = pcx[1]-pcx[0], uy = pcy[1]-pcy[0], uz = pcz[1]-pcz[0];
    float wx = pcx[2]-pcx[0], wy = pcy[2]-pcy[0], wz = pcz[2]-pcz[0];
    float nx = fmaf(uy, wz, -(uz*wy));
    float ny = fmaf(uz, wx, -(ux*wz));
    float nz = fmaf(ux, wy, -(uy*wx));
    float nn = sqrtf((nx*nx + ny*ny) + nz*nz) + 1e-8f;
    normals_out[t*3+0] = nx / nn;
    normals_out[t*3+1] = ny / nn;
    normals_out[t*3+2] = nz / nn;
}

__global__ __launch_bounds__(256) void raster(
    const float4* __restrict__ faceA,
    const float4* __restrict__ faceB,
    const float4* __restrict__ faceC,
    const int*    __restrict__ faces,
    const float*  __restrict__ uv,
    const float*  __restrict__ tex,
    float4* __restrict__ img)
{
#pragma clang fp contract(off)
    int t = blockIdx.x * blockDim.x + threadIdx.x;
    if (t >= B_ * HW_) return;
    int b   = t >> 14;      // / 16384
    int pix = t & (HW_ - 1);
    int y = pix >> 7;
    int x = pix & (W_ - 1);

    const double STEP = 2.0 / 127.0;
    float px = (float)(-1.0 + (double)x * STEP);
    float py = (float)( 1.0 - (double)y * STEP);

    const float4* fA = faceA + b * F_;
    const float4* fB = faceB + b * F_;
    const float4* fC = faceC + b * F_;

    float best = 1e10f;
    int bestI = 0;
#pragma unroll 4
    for (int f = 0; f < F_; ++f) {
        float4 A = fA[f];
        float4 Bv = fB[f];
        float4 C = fC[f];
        float dx = px - Bv.x;
        float dy = py - Bv.y;
        float n0 = A.x*dx + A.y*dy;
        float n1 = A.z*dx + A.w*dy;
        float l0 = n0 / Bv.z;
        float l1 = n1 / Bv.z;
        float l2 = 1.0f - l0 - l1;
        float zz = (l0*C.x + l1*C.y) + l2*C.z;
        bool ins = (l0 >= 0.0f) && (l1 >= 0.0f) && (l2 >= 0.0f)
                   && (Bv.w > 0.5f) && (zz > EPS_);
        float zm = ins ? zz : 1e10f;
        if (zm < best) { best = zm; bestI = f; }
    }

    bool hard = best < 1e10f;
    float r = 0.0f, g = 0.0f, bb = 0.0f, m = 0.0f;
    if (hard) {
        m = 1.0f;
        int fi = bestI;
        float4 A = fA[fi];
        float4 Bv = fB[fi];
        float dx = px - Bv.x;
        float dy = py - Bv.y;
        float n0 = A.x*dx + A.y*dy;
        float n1 = A.z*dx + A.w*dy;
        float l0 = n0 / Bv.z;
        float l1 = n1 / Bv.z;
        float l2 = 1.0f - l0 - l1;

        int i0 = faces[fi*3+0];
        int i1 = faces[fi*3+1];
        int i2 = faces[fi*3+2];
        const float* uvb = uv + b * P_ * 2;
        float u0 = uvb[i0*2+0], v0 = uvb[i0*2+1];
        float u1 = uvb[i1*2+0], v1 = uvb[i1*2+1];
        float u2 = uvb[i2*2+0], v2 = uvb[i2*2+1];
        float tu = (l0*u0 + l1*u1) + l2*u2;
        float tv = (l0*v0 + l1*v1) + l2*v2;
        // * hard == * 1.0f here
        float uc = fminf(fmaxf(tu, 0.0f), 1.0f);
        float vc = fminf(fmaxf(tv, 0.0f), 1.0f);
        int txi = (int)rintf(uc * 511.0f);
        int tyi = (int)rintf((1.0f - vc) * 511.0f);
        const float* tb = tex + b * 3 * 512 * 512;
        r  = tb[(0*512 + tyi)*512 + txi];
        g  = tb[(1*512 + tyi)*512 + txi];
        bb = tb[(2*512 + tyi)*512 + txi];
    }
    img[t] = make_float4(r, g, bb, m);
}

__global__ __launch_bounds__(256) void composite(
    const float4* __restrict__ img,
    const float*  __restrict__ ts,
    float* __restrict__ out)
{
    int pix = blockIdx.x * blockDim.x + threadIdx.x;
    if (pix >= HW_) return;

    float k[3];
    k[0] = ts[0*3+2];
    k[1] = ts[1*3+2];
    k[2] = ts[2*3+2];
    int o0 = 0, o1 = 1, o2 = 2;
    float k0 = k[0], k1 = k[1], k2 = k[2];
    // stable sort descending (argsort(-ts[:,2]), ties keep original order)
    if (k1 > k0) { int ti=o0; o0=o1; o1=ti; float tf=k0; k0=k1; k1=tf; }
    if (k2 > k1) { int ti=o1; o1=o2; o2=ti; float tf=k1; k1=k2; k2=tf; }
    if (k1 > k0) { int ti=o0; o0=o1; o1=ti; float tf=k0; k0=k1; k1=tf; }

    float4 v0 = img[o0*HW_ + pix];
    float4 v1 = img[o1*HW_ + pix];
    float4 v2 = img[o2*HW_ + pix];
    float4 sel = v0;
    if (v1.w > 0.5f) sel = v1;
    if (v2.w > 0.5f) sel = v2;

    out[pix*3+0] = sel.x;
    out[pix*3+1] = sel.y;
    out[pix*3+2] = sel.z;
    out[OFF_PROB + pix] = sel.w;  // improb
    out[OFF_FG   + pix] = sel.w;  // fg (== improb: probs==masks)
}

extern "C" void kernel_launch(void* const* d_in, const int* in_sizes, int n_in,
                              void* d_out, int out_size, void* d_ws, size_t ws_size,
                              hipStream_t stream) {
    const float* points = (const float*)d_in[0];
    const float* camrot = (const float*)d_in[1];
    const float* campos = (const float*)d_in[2];
    const float* proj   = (const float*)d_in[3];
    const float* uv     = (const float*)d_in[4];
    const float* tex    = (const float*)d_in[5];
    const float* ts     = (const float*)d_in[6];
    const int*   faces  = (const int*)d_in[7];
    float* out = (float*)d_out;

    char* ws = (char*)d_ws;
    float4* faceA = (float4*)(ws);
    float4* faceB = (float4*)(ws + 49152);
    float4* faceC = (float4*)(ws + 98304);
    float4* img   = (float4*)(ws + 147456);

    setup_faces<<<dim3((B_*F_ + 255)/256), dim3(256), 0, stream>>>(
        points, camrot, campos, proj, faces, faceA, faceB, faceC, out + OFF_NORM);
    raster<<<dim3((B_*HW_ + 255)/256), dim3(256), 0, stream>>>(
        faceA, faceB, faceC, faces, uv, tex, img);
    composite<<<dim3((HW_ + 255)/256), dim3(256), 0, stream>>>(img, ts, out);
}

// Round 4
// 134.346 us; speedup vs baseline: 2.3541x; 2.3541x over previous
//
#include <hip/hip_runtime.h>
#include <math.h>

#define B_ 3
#define P_ 768
#define F_ 1024
#define H_ 128
#define W_ 128
#define HW_ (H_*W_)
#define EPS_ 1e-8f
#define SEG_ 16                    // face-loop split factor
#define FSEG_ (F_/SEG_)            // 64 faces per segment-thread

// Output layout (flat concat, floats):
//   imrender (1,128,128,3) : offset 0,      49152
//   improb   (128,128,1)   : offset 49152,  16384
//   normals  (3,1024,3)    : offset 65536,   9216
//   fg       (1,128,128,1) : offset 74752,  16384
#define OFF_PROB   49152
#define OFF_NORM   65536
#define OFF_FG     74752

// Workspace layout (bytes):
//   faceA:  B*F float4  (e0x,e0y,e1x,e1y)        @ 0       (49152 B)
//   faceB:  B*F float4  (cx,cy,denom,validflag)  @ 49152
//   faceC:  B*F float4  (z0,z1,z2,0)             @ 98304
//   packed: B*HW u64    ((z_bits<<32)|faceidx)   @ 147456  (393216 B)

__global__ __launch_bounds__(256) void setup_faces(
    const float* __restrict__ points,
    const float* __restrict__ camrot,
    const float* __restrict__ campos,
    const float* __restrict__ proj,
    const int*   __restrict__ faces,
    float4* __restrict__ faceA,
    float4* __restrict__ faceB,
    float4* __restrict__ faceC,
    float*  __restrict__ normals_out)
{
#pragma clang fp contract(off)
    int t = blockIdx.x * blockDim.x + threadIdx.x;
    if (t >= B_ * F_) return;
    int b = t / F_;
    int f = t - b * F_;

    const float* R = camrot + b * 9;
    float cpx = campos[b*3+0], cpy = campos[b*3+1], cpz = campos[b*3+2];
    float pj0 = proj[0], pj1 = proj[1];

    float pcx[3], pcy[3], pcz[3], sx[3], sy[3];
    for (int v = 0; v < 3; ++v) {
        int vi = faces[f*3 + v];
        const float* P = points + (b*P_ + vi) * 3;
        float vx = P[0] - cpx;
        float vy = P[1] - cpy;
        float vz = P[2] - cpz;
        float qx = (vx*R[0] + vy*R[1]) + vz*R[2];
        float qy = (vx*R[3] + vy*R[4]) + vz*R[5];
        float qz = (vx*R[6] + vy*R[7]) + vz*R[8];
        pcx[v] = qx; pcy[v] = qy; pcz[v] = qz;
        float dz = qz + EPS_;
        sx[v] = (qx * pj0) / dz;
        sy[v] = (qy * pj1) / dz;
    }

    float ax = sx[0], ay = sy[0];
    float bx = sx[1], by = sy[1];
    float cx = sx[2], cy = sy[2];

    float e0x = by - cy;
    float e0y = cx - bx;
    float e1x = cy - ay;
    float e1y = ax - cx;
    float d = e0x*(ax - cx) + e0y*(ay - cy);
    float denom = d + EPS_;
    float valid = (fabsf(d) > EPS_) ? 1.0f : 0.0f;

    faceA[t] = make_float4(e0x, e0y, e1x, e1y);
    faceB[t] = make_float4(cx, cy, denom, valid);
    faceC[t] = make_float4(pcz[0], pcz[1], pcz[2], 0.0f);

    // normal: emulate XLA's LHS-fma contraction (validated bitwise, round 3).
    float ux = pcx[1]-pcx[0], uy = pcy[1]-pcy[0], uz = pcz[1]-pcz[0];
    float wx = pcx[2]-pcx[0], wy = pcy[2]-pcy[0], wz = pcz[2]-pcz[0];
    float nx = fmaf(uy, wz, -(uz*wy));
    float ny = fmaf(uz, wx, -(ux*wz));
    float nz = fmaf(ux, wy, -(uy*wx));
    float nn = sqrtf((nx*nx + ny*ny) + nz*nz) + 1e-8f;
    normals_out[t*3+0] = nx / nn;
    normals_out[t*3+1] = ny / nn;
    normals_out[t*3+2] = nz / nn;
}

// Depth pre-pass: each thread scans one 64-face segment for one pixel and
// atomicMin's a packed (z_bits, face_idx) u64. Positive-float bit patterns
// are value-monotone, so u64-min == (min z, then min idx) == jnp.argmin
// first-occurrence tie-break — associative, order-independent, deterministic.
__global__ __launch_bounds__(256) void raster_min(
    const float4* __restrict__ faceA,
    const float4* __restrict__ faceB,
    const float4* __restrict__ faceC,
    unsigned long long* __restrict__ packed)
{
#pragma clang fp contract(off)
    int pix = blockIdx.x * 256 + threadIdx.x;
    int s = blockIdx.y;
    int b = blockIdx.z;
    int y = pix >> 7;
    int x = pix & (W_ - 1);

    const double STEP = 2.0 / 127.0;
    float px = (float)(-1.0 + (double)x * STEP);
    float py = (float)( 1.0 - (double)y * STEP);

    const float4* fA = faceA + b * F_;
    const float4* fB = faceB + b * F_;
    const float4* fC = faceC + b * F_;

    int f0 = s * FSEG_;
    float best = 1e10f;
    int bestI = f0;
#pragma unroll 4
    for (int f = f0; f < f0 + FSEG_; ++f) {
        float4 A = fA[f];
        float4 Bv = fB[f];
        float4 C = fC[f];
        float dx = px - Bv.x;
        float dy = py - Bv.y;
        float n0 = A.x*dx + A.y*dy;
        float n1 = A.z*dx + A.w*dy;
        float l0 = n0 / Bv.z;
        float l1 = n1 / Bv.z;
        float l2 = 1.0f - l0 - l1;
        float zz = (l0*C.x + l1*C.y) + l2*C.z;
        bool ins = (l0 >= 0.0f) && (l1 >= 0.0f) && (l2 >= 0.0f)
                   && (Bv.w > 0.5f) && (zz > EPS_);
        float zm = ins ? zz : 1e10f;
        if (zm < best) { best = zm; bestI = f; }
    }

    unsigned long long pk =
        ((unsigned long long)__float_as_uint(best) << 32) | (unsigned)bestI;
    atomicMin(&packed[b * HW_ + pix], pk);
}

// Decode winner, shade (same arithmetic as the validated round-3 kernel),
// and composite all 3 batches in ts-sorted order — fused epilogue.
__global__ __launch_bounds__(256) void shade_composite(
    const float4* __restrict__ faceA,
    const float4* __restrict__ faceB,
    const int*    __restrict__ faces,
    const float*  __restrict__ uv,
    const float*  __restrict__ tex,
    const float*  __restrict__ ts,
    const unsigned long long* __restrict__ packed,
    float* __restrict__ out)
{
#pragma clang fp contract(off)
    int pix = blockIdx.x * 256 + threadIdx.x;
    int y = pix >> 7;
    int x = pix & (W_ - 1);

    const double STEP = 2.0 / 127.0;
    float px = (float)(-1.0 + (double)x * STEP);
    float py = (float)( 1.0 - (double)y * STEP);

    const unsigned MISS_BITS = __float_as_uint(1e10f);

    float rr[B_], gg[B_], bb_[B_], mm[B_];
    for (int b = 0; b < B_; ++b) {
        unsigned long long pk = packed[b * HW_ + pix];
        unsigned zbits = (unsigned)(pk >> 32);
        bool hard = zbits < MISS_BITS;
        float r = 0.0f, g = 0.0f, bl = 0.0f, m = 0.0f;
        if (hard) {
            m = 1.0f;
            int fi = (int)(unsigned)pk;   // global face idx within batch
            float4 A = faceA[b * F_ + fi];
            float4 Bv = faceB[b * F_ + fi];
            float dx = px - Bv.x;
            float dy = py - Bv.y;
            float n0 = A.x*dx + A.y*dy;
            float n1 = A.z*dx + A.w*dy;
            float l0 = n0 / Bv.z;
            float l1 = n1 / Bv.z;
            float l2 = 1.0f - l0 - l1;

            int i0 = faces[fi*3+0];
            int i1 = faces[fi*3+1];
            int i2 = faces[fi*3+2];
            const float* uvb = uv + b * P_ * 2;
            float u0 = uvb[i0*2+0], v0 = uvb[i0*2+1];
            float u1 = uvb[i1*2+0], v1 = uvb[i1*2+1];
            float u2 = uvb[i2*2+0], v2 = uvb[i2*2+1];
            float tu = (l0*u0 + l1*u1) + l2*u2;
            float tv = (l0*v0 + l1*v1) + l2*v2;
            float uc = fminf(fmaxf(tu, 0.0f), 1.0f);
            float vc = fminf(fmaxf(tv, 0.0f), 1.0f);
            int txi = (int)rintf(uc * 511.0f);
            int tyi = (int)rintf((1.0f - vc) * 511.0f);
            const float* tb = tex + b * 3 * 512 * 512;
            r  = tb[(0*512 + tyi)*512 + txi];
            g  = tb[(1*512 + tyi)*512 + txi];
            bl = tb[(2*512 + tyi)*512 + txi];
        }
        rr[b] = r; gg[b] = g; bb_[b] = bl; mm[b] = m;
    }

    // stable sort descending by ts[:,2] (argsort(-ts[:,2]))
    float k0 = ts[0*3+2], k1 = ts[1*3+2], k2 = ts[2*3+2];
    int o0 = 0, o1 = 1, o2 = 2;
    if (k1 > k0) { int ti=o0; o0=o1; o1=ti; float tf=k0; k0=k1; k1=tf; }
    if (k2 > k1) { int ti=o1; o1=o2; o2=ti; float tf=k1; k1=k2; k2=tf; }
    if (k1 > k0) { int ti=o0; o0=o1; o1=ti; float tf=k0; k0=k1; k1=tf; }

    float sr = rr[o0], sg = gg[o0], sb = bb_[o0], sm = mm[o0];
    if (mm[o1] > 0.5f) { sr = rr[o1]; sg = gg[o1]; sb = bb_[o1]; sm = mm[o1]; }
    if (mm[o2] > 0.5f) { sr = rr[o2]; sg = gg[o2]; sb = bb_[o2]; sm = mm[o2]; }

    out[pix*3+0] = sr;
    out[pix*3+1] = sg;
    out[pix*3+2] = sb;
    out[OFF_PROB + pix] = sm;  // improb
    out[OFF_FG   + pix] = sm;  // fg
}

extern "C" void kernel_launch(void* const* d_in, const int* in_sizes, int n_in,
                              void* d_out, int out_size, void* d_ws, size_t ws_size,
                              hipStream_t stream) {
    const float* points = (const float*)d_in[0];
    const float* camrot = (const float*)d_in[1];
    const float* campos = (const float*)d_in[2];
    const float* proj   = (const float*)d_in[3];
    const float* uv     = (const float*)d_in[4];
    const float* tex    = (const float*)d_in[5];
    const float* ts     = (const float*)d_in[6];
    const int*   faces  = (const int*)d_in[7];
    float* out = (float*)d_out;

    char* ws = (char*)d_ws;
    float4* faceA = (float4*)(ws);
    float4* faceB = (float4*)(ws + 49152);
    float4* faceC = (float4*)(ws + 98304);
    unsigned long long* packed = (unsigned long long*)(ws + 147456);

    // init packed cells to u64-max (ws is poisoned 0xAA each call)
    hipMemsetAsync(packed, 0xFF, (size_t)B_ * HW_ * 8, stream);

    setup_faces<<<dim3((B_*F_ + 255)/256), dim3(256), 0, stream>>>(
        points, camrot, campos, proj, faces, faceA, faceB, faceC, out + OFF_NORM);
    raster_min<<<dim3(HW_/256, SEG_, B_), dim3(256), 0, stream>>>(
        faceA, faceB, faceC, packed);
    shade_composite<<<dim3(HW_/256), dim3(256), 0, stream>>>(
        faceA, faceB, faces, uv, tex, ts, packed, out);
}

// Round 5
// 131.128 us; speedup vs baseline: 2.4119x; 1.0245x over previous
//
#include <hip/hip_runtime.h>
#include <math.h>

#define B_ 3
#define P_ 768
#define F_ 1024
#define H_ 128
#define W_ 128
#define HW_ (H_*W_)
#define EPS_ 1e-8f
#define SEG_ 16                    // face-loop split factor
#define FSEG_ (F_/SEG_)            // 64 faces per segment-thread

// Output layout (flat concat, floats):
//   imrender (1,128,128,3) : offset 0,      49152
//   improb   (128,128,1)   : offset 49152,  16384
//   normals  (3,1024,3)    : offset 65536,   9216
//   fg       (1,128,128,1) : offset 74752,  16384
#define OFF_PROB   49152
#define OFF_NORM   65536
#define OFF_FG     74752

// Workspace layout (bytes):
//   faceA:  B*F float4  (e0x,e0y,e1x,e1y)        @ 0       (49152 B)
//   faceB:  B*F float4  (cx,cy,denom,validflag)  @ 49152
//   faceC:  B*F float4  (z0,z1,z2,0)             @ 98304
//   faceD:  B*F float4  (xmin,xmax,ymin,ymax)    @ 147456  (bbox, NDC, pre-expanded)
//   packed: B*HW u64    ((z_bits<<32)|faceidx)   @ 196608  (393216 B)

__global__ __launch_bounds__(256) void setup_faces(
    const float* __restrict__ points,
    const float* __restrict__ camrot,
    const float* __restrict__ campos,
    const float* __restrict__ proj,
    const int*   __restrict__ faces,
    float4* __restrict__ faceA,
    float4* __restrict__ faceB,
    float4* __restrict__ faceC,
    float4* __restrict__ faceD,
    unsigned long long* __restrict__ packed,
    float*  __restrict__ normals_out)
{
#pragma clang fp contract(off)
    int t = blockIdx.x * blockDim.x + threadIdx.x;
    if (t >= B_ * F_) return;

    // fused init of the depth-atomic cells (replaces a memset dispatch):
    // 3072 threads x 16 cells covers all B*HW = 49152 cells.
    {
        unsigned long long* c = packed + (size_t)t * 16;
        for (int i = 0; i < 16; ++i) c[i] = 0xFFFFFFFFFFFFFFFFull;
    }

    int b = t / F_;
    int f = t - b * F_;

    const float* R = camrot + b * 9;
    float cpx = campos[b*3+0], cpy = campos[b*3+1], cpz = campos[b*3+2];
    float pj0 = proj[0], pj1 = proj[1];

    float pcx[3], pcy[3], pcz[3], sx[3], sy[3];
    for (int v = 0; v < 3; ++v) {
        int vi = faces[f*3 + v];
        const float* P = points + (b*P_ + vi) * 3;
        float vx = P[0] - cpx;
        float vy = P[1] - cpy;
        float vz = P[2] - cpz;
        float qx = (vx*R[0] + vy*R[1]) + vz*R[2];
        float qy = (vx*R[3] + vy*R[4]) + vz*R[5];
        float qz = (vx*R[6] + vy*R[7]) + vz*R[8];
        pcx[v] = qx; pcy[v] = qy; pcz[v] = qz;
        float dz = qz + EPS_;
        sx[v] = (qx * pj0) / dz;
        sy[v] = (qy * pj1) / dz;
    }

    float ax = sx[0], ay = sy[0];
    float bx = sx[1], by = sy[1];
    float cx = sx[2], cy = sy[2];

    float e0x = by - cy;
    float e0y = cx - bx;
    float e1x = cy - ay;
    float e1y = ax - cx;
    float d = e0x*(ax - cx) + e0y*(ay - cy);
    float denom = d + EPS_;
    float valid = (fabsf(d) > EPS_) ? 1.0f : 0.0f;

    faceA[t] = make_float4(e0x, e0y, e1x, e1y);
    faceB[t] = make_float4(cx, cy, denom, valid);
    faceC[t] = make_float4(pcz[0], pcz[1], pcz[2], 0.0f);

    // Conservative screen-space bbox (skip-hint only; never affects values).
    // A pixel whose ROUNDED barycentrics all pass >=0 lies within ~1e-5 px
    // of the exact hull; guard with 1.5 px in NDC (step = 2/127).
    if (valid > 0.5f) {
        const float M = 1.5f * (2.0f / 127.0f);
        float xmn = fminf(fminf(ax, bx), cx) - M;
        float xmx = fmaxf(fmaxf(ax, bx), cx) + M;
        float ymn = fminf(fminf(ay, by), cy) - M;
        float ymx = fmaxf(fmaxf(ay, by), cy) + M;
        faceD[t] = make_float4(xmn, xmx, ymn, ymx);
    } else {
        // degenerate (|d|<=eps): inside is impossible -> empty bbox
        faceD[t] = make_float4(1e30f, -1e30f, 1e30f, -1e30f);
    }

    // normal: emulate XLA's LHS-fma contraction (validated bitwise, round 3).
    float ux = pcx[1]-pcx[0], uy = pcy[1]-pcy[0], uz = pcz[1]-pcz[0];
    float wx = pcx[2]-pcx[0], wy = pcy[2]-pcy[0], wz = pcz[2]-pcz[0];
    float nx = fmaf(uy, wz, -(uz*wy));
    float ny = fmaf(uz, wx, -(ux*wz));
    float nz = fmaf(ux, wy, -(uy*wx));
    float nn = sqrtf((nx*nx + ny*ny) + nz*nz) + 1e-8f;
    normals_out[t*3+0] = nx / nn;
    normals_out[t*3+1] = ny / nn;
    normals_out[t*3+2] = nz / nn;
}

// Depth pre-pass with per-lane bbox culling. Positive-float bit patterns are
// value-monotone, so u64-min of (z_bits<<32)|idx == (min z, then min idx) ==
// jnp.argmin first-occurrence tie-break — order-independent, deterministic.
__global__ __launch_bounds__(256) void raster_min(
    const float4* __restrict__ faceA,
    const float4* __restrict__ faceB,
    const float4* __restrict__ faceC,
    const float4* __restrict__ faceD,
    unsigned long long* __restrict__ packed)
{
#pragma clang fp contract(off)
    int pix = blockIdx.x * 256 + threadIdx.x;
    int s = blockIdx.y;
    int b = blockIdx.z;
    int y = pix >> 7;
    int x = pix & (W_ - 1);

    const double STEP = 2.0 / 127.0;
    float px = (float)(-1.0 + (double)x * STEP);
    float py = (float)( 1.0 - (double)y * STEP);

    const float4* fA = faceA + b * F_;
    const float4* fB = faceB + b * F_;
    const float4* fC = faceC + b * F_;
    const float4* fD = faceD + b * F_;

    int f0 = s * FSEG_;
    float best = 1e10f;
    int bestI = f0;
    for (int f = f0; f < f0 + FSEG_; ++f) {
        float4 D = fD[f];
        if (px >= D.x && px <= D.y && py >= D.z && py <= D.w) {
            float4 A = fA[f];
            float4 Bv = fB[f];
            float4 C = fC[f];
            float dx = px - Bv.x;
            float dy = py - Bv.y;
            float n0 = A.x*dx + A.y*dy;
            float n1 = A.z*dx + A.w*dy;
            float l0 = n0 / Bv.z;
            float l1 = n1 / Bv.z;
            float l2 = 1.0f - l0 - l1;
            float zz = (l0*C.x + l1*C.y) + l2*C.z;
            bool ins = (l0 >= 0.0f) && (l1 >= 0.0f) && (l2 >= 0.0f)
                       && (Bv.w > 0.5f) && (zz > EPS_);
            float zm = ins ? zz : 1e10f;
            if (zm < best) { best = zm; bestI = f; }
        }
    }

    unsigned long long pk =
        ((unsigned long long)__float_as_uint(best) << 32) | (unsigned)bestI;
    atomicMin(&packed[b * HW_ + pix], pk);
}

// Decode winner, shade (same arithmetic as the validated round-3 kernel),
// and composite all 3 batches in ts-sorted order — fused epilogue.
__global__ __launch_bounds__(256) void shade_composite(
    const float4* __restrict__ faceA,
    const float4* __restrict__ faceB,
    const int*    __restrict__ faces,
    const float*  __restrict__ uv,
    const float*  __restrict__ tex,
    const float*  __restrict__ ts,
    const unsigned long long* __restrict__ packed,
    float* __restrict__ out)
{
#pragma clang fp contract(off)
    int pix = blockIdx.x * 256 + threadIdx.x;
    int y = pix >> 7;
    int x = pix & (W_ - 1);

    const double STEP = 2.0 / 127.0;
    float px = (float)(-1.0 + (double)x * STEP);
    float py = (float)( 1.0 - (double)y * STEP);

    const unsigned MISS_BITS = __float_as_uint(1e10f);

    float rr[B_], gg[B_], bb_[B_], mm[B_];
    for (int b = 0; b < B_; ++b) {
        unsigned long long pk = packed[b * HW_ + pix];
        unsigned zbits = (unsigned)(pk >> 32);
        bool hard = zbits < MISS_BITS;
        float r = 0.0f, g = 0.0f, bl = 0.0f, m = 0.0f;
        if (hard) {
            m = 1.0f;
            int fi = (int)(unsigned)pk;   // global face idx within batch
            float4 A = faceA[b * F_ + fi];
            float4 Bv = faceB[b * F_ + fi];
            float dx = px - Bv.x;
            float dy = py - Bv.y;
            float n0 = A.x*dx + A.y*dy;
            float n1 = A.z*dx + A.w*dy;
            float l0 = n0 / Bv.z;
            float l1 = n1 / Bv.z;
            float l2 = 1.0f - l0 - l1;

            int i0 = faces[fi*3+0];
            int i1 = faces[fi*3+1];
            int i2 = faces[fi*3+2];
            const float* uvb = uv + b * P_ * 2;
            float u0 = uvb[i0*2+0], v0 = uvb[i0*2+1];
            float u1 = uvb[i1*2+0], v1 = uvb[i1*2+1];
            float u2 = uvb[i2*2+0], v2 = uvb[i2*2+1];
            float tu = (l0*u0 + l1*u1) + l2*u2;
            float tv = (l0*v0 + l1*v1) + l2*v2;
            float uc = fminf(fmaxf(tu, 0.0f), 1.0f);
            float vc = fminf(fmaxf(tv, 0.0f), 1.0f);
            int txi = (int)rintf(uc * 511.0f);
            int tyi = (int)rintf((1.0f - vc) * 511.0f);
            const float* tb = tex + b * 3 * 512 * 512;
            r  = tb[(0*512 + tyi)*512 + txi];
            g  = tb[(1*512 + tyi)*512 + txi];
            bl = tb[(2*512 + tyi)*512 + txi];
        }
        rr[b] = r; gg[b] = g; bb_[b] = bl; mm[b] = m;
    }

    // stable sort descending by ts[:,2] (argsort(-ts[:,2]))
    float k0 = ts[0*3+2], k1 = ts[1*3+2], k2 = ts[2*3+2];
    int o0 = 0, o1 = 1, o2 = 2;
    if (k1 > k0) { int ti=o0; o0=o1; o1=ti; float tf=k0; k0=k1; k1=tf; }
    if (k2 > k1) { int ti=o1; o1=o2; o2=ti; float tf=k1; k1=k2; k2=tf; }
    if (k1 > k0) { int ti=o0; o0=o1; o1=ti; float tf=k0; k0=k1; k1=tf; }

    float sr = rr[o0], sg = gg[o0], sb = bb_[o0], sm = mm[o0];
    if (mm[o1] > 0.5f) { sr = rr[o1]; sg = gg[o1]; sb = bb_[o1]; sm = mm[o1]; }
    if (mm[o2] > 0.5f) { sr = rr[o2]; sg = gg[o2]; sb = bb_[o2]; sm = mm[o2]; }

    out[pix*3+0] = sr;
    out[pix*3+1] = sg;
    out[pix*3+2] = sb;
    out[OFF_PROB + pix] = sm;  // improb
    out[OFF_FG   + pix] = sm;  // fg
}

extern "C" void kernel_launch(void* const* d_in, const int* in_sizes, int n_in,
                              void* d_out, int out_size, void* d_ws, size_t ws_size,
                              hipStream_t stream) {
    const float* points = (const float*)d_in[0];
    const float* camrot = (const float*)d_in[1];
    const float* campos = (const float*)d_in[2];
    const float* proj   = (const float*)d_in[3];
    const float* uv     = (const float*)d_in[4];
    const float* tex    = (const float*)d_in[5];
    const float* ts     = (const float*)d_in[6];
    const int*   faces  = (const int*)d_in[7];
    float* out = (float*)d_out;

    char* ws = (char*)d_ws;
    float4* faceA = (float4*)(ws);
    float4* faceB = (float4*)(ws + 49152);
    float4* faceC = (float4*)(ws + 98304);
    float4* faceD = (float4*)(ws + 147456);
    unsigned long long* packed = (unsigned long long*)(ws + 196608);

    setup_faces<<<dim3((B_*F_ + 255)/256), dim3(256), 0, stream>>>(
        points, camrot, campos, proj, faces, faceA, faceB, faceC, faceD,
        packed, out + OFF_NORM);
    raster_min<<<dim3(HW_/256, SEG_, B_), dim3(256), 0, stream>>>(
        faceA, faceB, faceC, faceD, packed);
    shade_composite<<<dim3(HW_/256), dim3(256), 0, stream>>>(
        faceA, faceB, faces, uv, tex, ts, packed, out);
}

// Round 6
// 89.946 us; speedup vs baseline: 3.5162x; 1.4579x over previous
//
#include <hip/hip_runtime.h>
#include <math.h>

#define B_ 3
#define P_ 768
#define F_ 1024
#define H_ 128
#define W_ 128
#define HW_ (H_*W_)
#define EPS_ 1e-8f

// Output layout (flat concat, floats):
//   imrender (1,128,128,3) : offset 0,      49152
//   improb   (128,128,1)   : offset 49152,  16384
//   normals  (3,1024,3)    : offset 65536,   9216
//   fg       (1,128,128,1) : offset 74752,  16384
#define OFF_PROB   49152
#define OFF_NORM   65536
#define OFF_FG     74752

// Workspace layout (bytes):
//   faceA:  B*F float4  (e0x,e0y,e1x,e1y)        @ 0       (49152 B)
//   faceB:  B*F float4  (cx,cy,denom,valid)      @ 49152
//   packed: B*HW u64    ((z_bits<<32)|faceidx)   @ 98304   (393216 B)

// Forward rasterizer: ONE WAVE PER FACE. The wave computes its face's setup
// in-register (all lanes redundantly — same values), lane 0 writes normals +
// the per-face data the shading pass needs, then lanes stripe over the face's
// conservative pixel bbox and atomicMin a packed (z_bits, idx) u64 per pixel.
// Positive-float bits are value-monotone, so u64-min == (min z, then min idx)
// == jnp.argmin first-occurrence tie-break — order-independent across waves.
__global__ __launch_bounds__(256) void raster_fwd(
    const float* __restrict__ points,
    const float* __restrict__ camrot,
    const float* __restrict__ campos,
    const float* __restrict__ proj,
    const int*   __restrict__ faces,
    float4* __restrict__ faceA,
    float4* __restrict__ faceB,
    unsigned long long* __restrict__ packed,
    float*  __restrict__ normals_out)
{
#pragma clang fp contract(off)
    int wid  = blockIdx.x * 4 + (threadIdx.x >> 6);   // global wave = face slot
    int lane = threadIdx.x & 63;
    int b = wid / F_;
    int f = wid - b * F_;

    // ---- per-face setup (bit-identical expressions to the validated r3/r4
    //      setup_faces, compiled under contract(off)) ----
    const float* R = camrot + b * 9;
    float cpx = campos[b*3+0], cpy = campos[b*3+1], cpz = campos[b*3+2];
    float pj0 = proj[0], pj1 = proj[1];

    float pcx[3], pcy[3], pcz[3], sx[3], sy[3];
    for (int v = 0; v < 3; ++v) {
        int vi = faces[f*3 + v];
        const float* P = points + (b*P_ + vi) * 3;
        float vx = P[0] - cpx;
        float vy = P[1] - cpy;
        float vz = P[2] - cpz;
        float qx = (vx*R[0] + vy*R[1]) + vz*R[2];
        float qy = (vx*R[3] + vy*R[4]) + vz*R[5];
        float qz = (vx*R[6] + vy*R[7]) + vz*R[8];
        pcx[v] = qx; pcy[v] = qy; pcz[v] = qz;
        float dz = qz + EPS_;
        sx[v] = (qx * pj0) / dz;
        sy[v] = (qy * pj1) / dz;
    }

    float ax = sx[0], ay = sy[0];
    float bx = sx[1], by = sy[1];
    float cx = sx[2], cy = sy[2];

    float e0x = by - cy;
    float e0y = cx - bx;
    float e1x = cy - ay;
    float e1y = ax - cx;
    float d = e0x*(ax - cx) + e0y*(ay - cy);
    float denom = d + EPS_;
    bool valid = fabsf(d) > EPS_;
    float z0 = pcz[0], z1 = pcz[1], z2 = pcz[2];

    if (lane == 0) {
        faceA[wid] = make_float4(e0x, e0y, e1x, e1y);
        faceB[wid] = make_float4(cx, cy, denom, valid ? 1.0f : 0.0f);

        // normal: emulate XLA's LHS-fma contraction (validated bitwise, r3).
        float ux = pcx[1]-pcx[0], uy = pcy[1]-pcy[0], uz = pcz[1]-pcz[0];
        float wx = pcx[2]-pcx[0], wy = pcy[2]-pcy[0], wz = pcz[2]-pcz[0];
        float nx = fmaf(uy, wz, -(uz*wy));
        float ny = fmaf(uz, wx, -(ux*wz));
        float nz = fmaf(ux, wy, -(uy*wx));
        float nn = sqrtf((nx*nx + ny*ny) + nz*nz) + 1e-8f;
        normals_out[wid*3+0] = nx / nn;
        normals_out[wid*3+1] = ny / nn;
        normals_out[wid*3+2] = nz / nn;
    }

    if (!valid) return;   // inside==false for every pixel of this face

    // ---- conservative pixel-index bbox (1-px guard >> ~1e-4 px rounding
    //      uncertainty of the >=0 tests; pure skip-hint superset) ----
    float gx0 = (ax + 1.0f) * 63.5f;
    float gx1 = (bx + 1.0f) * 63.5f;
    float gx2 = (cx + 1.0f) * 63.5f;
    float gy0 = (1.0f - ay) * 63.5f;
    float gy1 = (1.0f - by) * 63.5f;
    float gy2 = (1.0f - cy) * 63.5f;
    int xlo = max(0,   (int)ceilf (fminf(fminf(gx0,gx1),gx2) - 1.0f));
    int xhi = min(127, (int)floorf(fmaxf(fmaxf(gx0,gx1),gx2) + 1.0f));
    int ylo = max(0,   (int)ceilf (fminf(fminf(gy0,gy1),gy2) - 1.0f));
    int yhi = min(127, (int)floorf(fmaxf(fmaxf(gy0,gy1),gy2) + 1.0f));
    int wX = xhi - xlo + 1;
    int wY = yhi - ylo + 1;
    if (wX <= 0 || wY <= 0) return;
    int N = wX * wY;

    // incremental i -> (xx,yy) decomposition: one div at entry, O(1)/step
    int q64 = 64 / wX;
    int r64 = 64 - q64 * wX;
    int yy = lane / wX;
    int xx = lane - yy * wX;

    const double STEP = 2.0 / 127.0;
    unsigned long long* cells = packed + b * HW_;

    for (int i = lane; i < N; i += 64) {
        int X = xlo + xx;
        int Y = ylo + yy;
        float px = (float)(-1.0 + (double)X * STEP);
        float py = (float)( 1.0 - (double)Y * STEP);
        float dx = px - cx;
        float dy = py - cy;
        float n0 = e0x*dx + e0y*dy;
        float n1 = e1x*dx + e1y*dy;
        float l0 = n0 / denom;
        float l1 = n1 / denom;
        float l2 = 1.0f - l0 - l1;
        float zz = (l0*z0 + l1*z1) + l2*z2;
        if (l0 >= 0.0f && l1 >= 0.0f && l2 >= 0.0f && zz > EPS_) {
            unsigned long long pk =
                ((unsigned long long)__float_as_uint(zz) << 32) | (unsigned)f;
            atomicMin(&cells[Y * W_ + X], pk);
        }
        xx += r64; yy += q64;
        if (xx >= wX) { xx -= wX; yy += 1; }
    }
}

// Decode winner, shade (same arithmetic as the validated round-3 kernel),
// and composite all 3 batches in ts-sorted order — fused epilogue.
__global__ __launch_bounds__(256) void shade_composite(
    const float4* __restrict__ faceA,
    const float4* __restrict__ faceB,
    const int*    __restrict__ faces,
    const float*  __restrict__ uv,
    const float*  __restrict__ tex,
    const float*  __restrict__ ts,
    const unsigned long long* __restrict__ packed,
    float* __restrict__ out)
{
#pragma clang fp contract(off)
    int pix = blockIdx.x * 256 + threadIdx.x;
    int y = pix >> 7;
    int x = pix & (W_ - 1);

    const double STEP = 2.0 / 127.0;
    float px = (float)(-1.0 + (double)x * STEP);
    float py = (float)( 1.0 - (double)y * STEP);

    const unsigned MISS_BITS = __float_as_uint(1e10f);

    float rr[B_], gg[B_], bb_[B_], mm[B_];
    for (int b = 0; b < B_; ++b) {
        unsigned long long pk = packed[b * HW_ + pix];
        unsigned zbits = (unsigned)(pk >> 32);
        bool hard = zbits < MISS_BITS;
        float r = 0.0f, g = 0.0f, bl = 0.0f, m = 0.0f;
        if (hard) {
            m = 1.0f;
            int fi = (int)(unsigned)pk;   // face idx within batch
            float4 A = faceA[b * F_ + fi];
            float4 Bv = faceB[b * F_ + fi];
            float dx = px - Bv.x;
            float dy = py - Bv.y;
            float n0 = A.x*dx + A.y*dy;
            float n1 = A.z*dx + A.w*dy;
            float l0 = n0 / Bv.z;
            float l1 = n1 / Bv.z;
            float l2 = 1.0f - l0 - l1;

            int i0 = faces[fi*3+0];
            int i1 = faces[fi*3+1];
            int i2 = faces[fi*3+2];
            const float* uvb = uv + b * P_ * 2;
            float u0 = uvb[i0*2+0], v0 = uvb[i0*2+1];
            float u1 = uvb[i1*2+0], v1 = uvb[i1*2+1];
            float u2 = uvb[i2*2+0], v2 = uvb[i2*2+1];
            float tu = (l0*u0 + l1*u1) + l2*u2;
            float tv = (l0*v0 + l1*v1) + l2*v2;
            float uc = fminf(fmaxf(tu, 0.0f), 1.0f);
            float vc = fminf(fmaxf(tv, 0.0f), 1.0f);
            int txi = (int)rintf(uc * 511.0f);
            int tyi = (int)rintf((1.0f - vc) * 511.0f);
            const float* tb = tex + b * 3 * 512 * 512;
            r  = tb[(0*512 + tyi)*512 + txi];
            g  = tb[(1*512 + tyi)*512 + txi];
            bl = tb[(2*512 + tyi)*512 + txi];
        }
        rr[b] = r; gg[b] = g; bb_[b] = bl; mm[b] = m;
    }

    // stable sort descending by ts[:,2] (argsort(-ts[:,2]))
    float k0 = ts[0*3+2], k1 = ts[1*3+2], k2 = ts[2*3+2];
    int o0 = 0, o1 = 1, o2 = 2;
    if (k1 > k0) { int ti=o0; o0=o1; o1=ti; float tf=k0; k0=k1; k1=tf; }
    if (k2 > k1) { int ti=o1; o1=o2; o2=ti; float tf=k1; k1=k2; k2=tf; }
    if (k1 > k0) { int ti=o0; o0=o1; o1=ti; float tf=k0; k0=k1; k1=tf; }

    float sr = rr[o0], sg = gg[o0], sb = bb_[o0], sm = mm[o0];
    if (mm[o1] > 0.5f) { sr = rr[o1]; sg = gg[o1]; sb = bb_[o1]; sm = mm[o1]; }
    if (mm[o2] > 0.5f) { sr = rr[o2]; sg = gg[o2]; sb = bb_[o2]; sm = mm[o2]; }

    out[pix*3+0] = sr;
    out[pix*3+1] = sg;
    out[pix*3+2] = sb;
    out[OFF_PROB + pix] = sm;  // improb
    out[OFF_FG   + pix] = sm;  // fg
}

extern "C" void kernel_launch(void* const* d_in, const int* in_sizes, int n_in,
                              void* d_out, int out_size, void* d_ws, size_t ws_size,
                              hipStream_t stream) {
    const float* points = (const float*)d_in[0];
    const float* camrot = (const float*)d_in[1];
    const float* campos = (const float*)d_in[2];
    const float* proj   = (const float*)d_in[3];
    const float* uv     = (const float*)d_in[4];
    const float* tex    = (const float*)d_in[5];
    const float* ts     = (const float*)d_in[6];
    const int*   faces  = (const int*)d_in[7];
    float* out = (float*)d_out;

    char* ws = (char*)d_ws;
    float4* faceA = (float4*)(ws);
    float4* faceB = (float4*)(ws + 49152);
    unsigned long long* packed = (unsigned long long*)(ws + 98304);

    // init depth cells to u64-max (miss). Misses never write in fwd raster.
    hipMemsetAsync(packed, 0xFF, (size_t)B_ * HW_ * 8, stream);

    raster_fwd<<<dim3(B_*F_/4), dim3(256), 0, stream>>>(
        points, camrot, campos, proj, faces, faceA, faceB, packed,
        out + OFF_NORM);
    shade_composite<<<dim3(HW_/256), dim3(256), 0, stream>>>(
        faceA, faceB, faces, uv, tex, ts, packed, out);
}